// Round 4
// baseline (244.254 us; speedup 1.0000x reference)
//
#include <hip/hip_runtime.h>

// CustomConv2d: 3x3 conv, stride 1, pad 1. B=32, Cin=128, H=W=56, Cout=256.
// fp32 in/out (round-1 NaN proved it); device-side dtype self-detector kept.
//
// Implicit GEMM, internally bf16. M=cout(256), N=b*h*w(100352), K=cin*9(1152).
// Round-4: wave-specialized producer/consumer pipeline (the documented path
// past the 2-barrier plateau): 4 consumer waves (MFMA) + 2 producer waves
// (global_load_lds DMA), 4x16KB LDS ring, step-tagged ready/freed flags,
// NO __syncthreads in the K-loop. Consumer geometry identical to the
// twice-verified round-2 kernel (BK=32, 16x16x32 bf16, XOR chunk swizzle).

typedef __attribute__((ext_vector_type(8))) short short8;
typedef __attribute__((ext_vector_type(4))) float floatx4;

typedef __attribute__((address_space(1))) const void* gas_ptr;
typedef __attribute__((address_space(3))) void* las_ptr;

__device__ static inline void gl2lds16(const void* g, void* l) {
    __builtin_amdgcn_global_load_lds((gas_ptr)g, (las_ptr)l, 16, 0, 0);
}

__device__ static inline float bf2f(unsigned short u) {
    union { unsigned int i; float f; } x; x.i = ((unsigned int)u) << 16; return x.f;
}
__device__ static inline unsigned short f2bf(float f) {
    union { float f; unsigned int i; } x; x.f = f;
    unsigned int r = (x.i + 0x7FFFu + ((x.i >> 16) & 1u)) >> 16;  // RNE
    return (unsigned short)r;
}

// ---------------- dtype detector: flag=1 if x looks like bf16 --------------
__global__ void detect_dtype(const unsigned int* __restrict__ x,
                             unsigned int* __restrict__ flag) {
    int cnt = 0;
    for (int r = 0; r < 4; ++r) {
        unsigned int w = x[r * 64 + threadIdx.x];
        unsigned short lo = (unsigned short)(w & 0xFFFFu);
        int e = (lo >> 7) & 0xFF;
        bool plaus = (lo == 0) || (e >= 96 && e <= 144);
        unsigned long long b = __ballot(plaus);
        if (threadIdx.x == 0) cnt += (int)__popcll(b);
    }
    if (threadIdx.x == 0) *flag = (cnt >= 205) ? 1u : 0u;  // >=80% of 256
}

// ---------------- weight repack -> [9][256][128] bf16 ----------------------
__global__ void wt_repack(const void* __restrict__ wsrc,
                          unsigned short* __restrict__ wt,
                          const unsigned int* __restrict__ flag) {
    const bool isbf = (*flag != 0);
    int idx = blockIdx.x * 256 + threadIdx.x;       // 294912 total, grid=1152
    int ci  = idx & 127;
    int co  = (idx >> 7) & 255;
    int off = idx >> 15;                            // 0..8 = dh*3+dw
    size_t s = (size_t)(co * 128 + ci) * 9 + off;
    float v = isbf ? bf2f(((const unsigned short*)wsrc)[s])
                   : ((const float*)wsrc)[s];
    wt[idx] = f2bf(v);
}

// ------- x NCHW -> padded NHWC bf16 [32][58][58][128], LDS transpose -------
__global__ __launch_bounds__(256) void x_repack(
    const void* __restrict__ xsrc, unsigned short* __restrict__ xp,
    const unsigned int* __restrict__ flag) {
    __shared__ unsigned short tile[56 * 130];   // pad 130: conflict-free
    const bool isbf = (*flag != 0);
    const int bh  = blockIdx.x;                 // 32*58 blocks
    const int b   = bh / 58, hp = bh - b * 58;  // hp in [0,58)
    const int tid = threadIdx.x;
    unsigned short* row = xp + (size_t)(b * 58 + hp) * 58 * 128;
    if (hp == 0 || hp == 57) {                  // top/bottom pad rows
        uint4 z; z.x = z.y = z.z = z.w = 0u;
        uint4* r = (uint4*)row;
        for (int t = tid; t < 928; t += 256) r[t] = z;
        return;
    }
    const int h = hp - 1;
    if (isbf) {
        const unsigned short* xs =
            (const unsigned short*)xsrc + (size_t)b * 128 * 3136 + h * 56;
#pragma unroll
        for (int it = 0; it < 7; ++it) {        // 1792 items = 128ci x 14 w4
            int idx = it * 256 + tid;
            int ci = idx / 14, w4 = idx - ci * 14;
            ushort4 v = *(const ushort4*)(xs + (size_t)ci * 3136 + w4 * 4);
            tile[(w4 * 4 + 0) * 130 + ci] = v.x;
            tile[(w4 * 4 + 1) * 130 + ci] = v.y;
            tile[(w4 * 4 + 2) * 130 + ci] = v.z;
            tile[(w4 * 4 + 3) * 130 + ci] = v.w;
        }
    } else {
        const float* xs = (const float*)xsrc + (size_t)b * 128 * 3136 + h * 56;
#pragma unroll
        for (int it = 0; it < 7; ++it) {
            int idx = it * 256 + tid;
            int ci = idx / 14, w4 = idx - ci * 14;
            float4 v = *(const float4*)(xs + (size_t)ci * 3136 + w4 * 4);
            tile[(w4 * 4 + 0) * 130 + ci] = f2bf(v.x);
            tile[(w4 * 4 + 1) * 130 + ci] = f2bf(v.y);
            tile[(w4 * 4 + 2) * 130 + ci] = f2bf(v.z);
            tile[(w4 * 4 + 3) * 130 + ci] = f2bf(v.w);
        }
    }
    __syncthreads();
#pragma unroll
    for (int it = 0; it < 4; ++it) {
        int k = it * 256 + tid;                 // 928 chunks of 16B
        if (k >= 928) break;
        int wq = k >> 4, cc = k & 15;
        uint4 v;
        if (wq == 0 || wq == 57) { v.x = v.y = v.z = v.w = 0u; }
        else {
            const unsigned short* p = &tile[(wq - 1) * 130 + cc * 8];
            union { unsigned short s[8]; uint4 u; } pk;
#pragma unroll
            for (int j = 0; j < 8; ++j) pk.s[j] = p[j];
            v = pk.u;
        }
        *(uint4*)(row + wq * 128 + cc * 8) = v;
    }
}

// -------- main: wave-specialized producer/consumer implicit GEMM -----------
__global__ __launch_bounds__(384) void conv_mfma(
    const unsigned short* __restrict__ xp,   // [32][58][58][128] bf16
    const unsigned short* __restrict__ wt,   // [9][256][128] bf16
    const void* __restrict__ bias,           // [256] fp32 or bf16
    void* __restrict__ out,                  // [32][256][56][56] fp32 or bf16
    const unsigned int* __restrict__ flag)
{
    __shared__ __align__(16) char lds[65536];   // 4 buffers x (A 8KB | B 8KB)
    __shared__ unsigned ready[4];               // step tag: s+1 when loaded
    __shared__ unsigned freed[4];               // 4 per consumed cycle
    const bool isbf = (*flag != 0);
    const int tid   = threadIdx.x;
    const int lane  = tid & 63;
    const int wv    = tid >> 6;        // 0..3 consumers, 4..5 producers
    const int ntile = blockIdx.x;      // 0..783 (spatial)
    const int mtile = blockIdx.y;      // 0..1   (cout)

    if (tid < 4) { ready[tid] = 0u; freed[tid] = 0u; }
    __syncthreads();                   // the ONLY barrier

    if (wv >= 4) {
        // ================= producer waves =================
        const int pid = wv - 4;                          // 0 or 1
        const int srp = lane >> 2;                       // row-in-16 group
        const int clg = (lane & 3) ^ ((lane >> 3) & 3);  // XOR chunk swizzle
        const unsigned short* aB = wt + (mtile * 128 + srp) * 128 + clg * 8;
        size_t bRow[8];
#pragma unroll
        for (int i = 0; i < 8; ++i) {
            const int n = ntile * 128 + i * 16 + srp;
            const int b = n / 3136, s2 = n - b * 3136;
            const int h = s2 / 56,  w = s2 - h * 56;
            bRow[i] = ((size_t)(b * 58 + h) * 58 + w) * 128 + clg * 8;
        }
        for (int s = pid; s < 36; s += 2) {
            const int bf_ = s & 3, cyc = s >> 2;
            if (cyc > 0) {
                const unsigned gate = 4u * (unsigned)cyc;
                while (__hip_atomic_load(&freed[bf_], __ATOMIC_ACQUIRE,
                                         __HIP_MEMORY_SCOPE_WORKGROUP) < gate)
                    __builtin_amdgcn_s_sleep(1);
            }
            char* buf = lds + bf_ * 16384;
            const int off = s >> 2, kb = (s & 3) << 5;   // off 0..8, kb 0..96
            const int dh = off / 3, dw = off - dh * 3;
            const int aoff = off * 32768 + kb;
            const int boff = (dh * 58 + dw) * 128 + kb;
#pragma unroll
            for (int i = 0; i < 8; ++i)
                gl2lds16(aB + i * 2048 + aoff, buf + i * 1024);
#pragma unroll
            for (int i = 0; i < 8; ++i)
                gl2lds16(xp + bRow[i] + boff, buf + 8192 + i * 1024);
            __builtin_amdgcn_s_waitcnt(0x3F70);          // vmcnt(0), this wave only
            if (lane == 0)
                __hip_atomic_store(&ready[bf_], (unsigned)(s + 1),
                                   __ATOMIC_RELEASE, __HIP_MEMORY_SCOPE_WORKGROUP);
        }
        return;
    }

    // ================= consumer waves =================
    const int mbase = (wv >> 1) * 64 + (lane & 15);
    const int nbase = (wv & 1) * 64 + (lane & 15);
    const int ph    = (lane >> 4) ^ (((lane & 15) >> 1) & 3);
    floatx4 acc[4][4] = {};

#pragma unroll 4
    for (int s = 0; s < 36; ++s) {
        const int bf_ = s & 3;
        while (__hip_atomic_load(&ready[bf_], __ATOMIC_ACQUIRE,
                                 __HIP_MEMORY_SCOPE_WORKGROUP) < (unsigned)(s + 1))
            ;
        const char* la = lds + bf_ * 16384;
        const char* lb = la + 8192;
        short8 af[4], bfr[4];
#pragma unroll
        for (int t = 0; t < 4; ++t) {
            af[t]  = *(const short8*)(la + (mbase + t * 16) * 64 + ph * 16);
            bfr[t] = *(const short8*)(lb + (nbase + t * 16) * 64 + ph * 16);
        }
#pragma unroll
        for (int i = 0; i < 4; ++i)
#pragma unroll
            for (int j = 0; j < 4; ++j)
                acc[i][j] = __builtin_amdgcn_mfma_f32_16x16x32_bf16(
                    af[i], bfr[j], acc[i][j], 0, 0, 0);
        // release-add: fence drains this wave's ds_reads before buffer reuse
        if (lane == 0)
            __hip_atomic_fetch_add(&freed[bf_], 1u, __ATOMIC_RELEASE,
                                   __HIP_MEMORY_SCOPE_WORKGROUP);
    }

    // ---- epilogue: D[row=cout(quad*4+reg)][col=spatial(lane&15)]
    const int q = lane >> 4;
#pragma unroll
    for (int j = 0; j < 4; ++j) {
        const int n = ntile * 128 + (wv & 1) * 64 + j * 16 + (lane & 15);
        const int b = n / 3136;
        const int s = n - b * 3136;
#pragma unroll
        for (int i = 0; i < 4; ++i) {
            const int co = mtile * 128 + (wv >> 1) * 64 + i * 16 + q * 4;
            float bv[4];
            if (isbf) {
                const ushort4 bb = *(const ushort4*)((const unsigned short*)bias + co);
                bv[0] = bf2f(bb.x); bv[1] = bf2f(bb.y);
                bv[2] = bf2f(bb.z); bv[3] = bf2f(bb.w);
            } else {
                const float4 bb = *(const float4*)((const float*)bias + co);
                bv[0] = bb.x; bv[1] = bb.y; bv[2] = bb.z; bv[3] = bb.w;
            }
#pragma unroll
            for (int r = 0; r < 4; ++r) {
                const float v = acc[i][j][r] + bv[r];
                const size_t o = (size_t)b * 802816 + (size_t)(co + r) * 3136 + s;
                if (isbf) ((unsigned short*)out)[o] = f2bf(v);
                else      ((float*)out)[o] = v;
            }
        }
    }
}

// ---------------- fallback: naive direct conv fp32 (if ws too small) -------
__global__ void conv_naive(const float* __restrict__ x,
                           const float* __restrict__ w,
                           const float* __restrict__ bias,
                           float* __restrict__ out) {
    long long i = (long long)blockIdx.x * 256 + threadIdx.x;
    if (i >= 25690112LL) return;
    int wo = (int)(i % 56); long long t = i / 56;
    int ho = (int)(t % 56); t /= 56;
    int co = (int)(t % 256); int b = (int)(t / 256);
    float acc = bias[co];
    for (int ci = 0; ci < 128; ++ci)
        for (int dh = 0; dh < 3; ++dh) {
            int hi = ho + dh - 1; if ((unsigned)hi >= 56u) continue;
            for (int dw = 0; dw < 3; ++dw) {
                int wi = wo + dw - 1; if ((unsigned)wi >= 56u) continue;
                acc += x[((size_t)(b * 128 + ci) * 56 + hi) * 56 + wi] *
                       w[((co * 128 + ci) * 3 + dh) * 3 + dw];
            }
        }
    out[i] = acc;
}

extern "C" void kernel_launch(void* const* d_in, const int* in_sizes, int n_in,
                              void* d_out, int out_size, void* d_ws, size_t ws_size,
                              hipStream_t stream) {
    const void* x    = d_in[0];
    const void* w    = d_in[1];
    const void* bias = d_in[2];
    // d_in[3] = approximate (scalar, does not affect exact math) — unused.

    const size_t xp_bytes = (size_t)32 * 58 * 58 * 128 * 2;   // 27,557,888
    const size_t wt_off   = xp_bytes;
    const size_t wt_bytes = (size_t)9 * 256 * 128 * 2;        // 589,824
    const size_t fl_off   = wt_off + wt_bytes;                // 4B aligned
    const size_t need     = fl_off + 64;

    if (ws_size >= need) {
        unsigned short* xp = (unsigned short*)d_ws;
        unsigned short* wt = (unsigned short*)((char*)d_ws + wt_off);
        unsigned int* flag = (unsigned int*)((char*)d_ws + fl_off);
        detect_dtype<<<1, 64, 0, stream>>>((const unsigned int*)x, flag);
        x_repack<<<32 * 58, 256, 0, stream>>>(x, xp, flag);
        wt_repack<<<1152, 256, 0, stream>>>(w, wt, flag);
        dim3 grid(784, 2, 1);
        conv_mfma<<<grid, 384, 0, stream>>>(xp, wt, bias, d_out, flag);
    } else {
        conv_naive<<<(25690112 + 255) / 256, 256, 0, stream>>>(
            (const float*)x, (const float*)w, (const float*)bias, (float*)d_out);
    }
}

// Round 5
// 224.718 us; speedup vs baseline: 1.0869x; 1.0869x over previous
//
#include <hip/hip_runtime.h>

// CustomConv2d: 3x3 conv, stride 1, pad 1. B=32, Cin=128, H=W=56, Cout=256.
// fp32 in/out (round-1 NaN proved it); per-wave dtype self-detection keeps
// robustness without a separate serialized detect dispatch.
//
// Implicit GEMM, internally bf16. M=cout(256), N=b*h*w(100352), K=cin*9(1152).
// Round-5: same wave-specialized producer/consumer pipeline as round-4
// (4 consumer + 2 producer waves, step-tagged flags, no __syncthreads in the
// K-loop) but NBUF=3 -> 48KB LDS so 2-3 blocks co-reside per CU. Round-4's
// counters showed 1 block/CU (Occupancy 17.6%) => 1 consumer wave/SIMD =>
// every ds_read/spin cycle was an un-hideable MFMA-pipe bubble (per-SIMD
// MFMA cost ~19.4cyc => util pinned at 20%). Multi-block residency lets
// independent blocks fill each other's bubbles.

typedef __attribute__((ext_vector_type(8))) short short8;
typedef __attribute__((ext_vector_type(4))) float floatx4;

typedef __attribute__((address_space(1))) const void* gas_ptr;
typedef __attribute__((address_space(3))) void* las_ptr;

__device__ static inline void gl2lds16(const void* g, void* l) {
    __builtin_amdgcn_global_load_lds((gas_ptr)g, (las_ptr)l, 16, 0, 0);
}

__device__ static inline float bf2f(unsigned short u) {
    union { unsigned int i; float f; } x; x.i = ((unsigned int)u) << 16; return x.f;
}
__device__ static inline unsigned short f2bf(float f) {
    union { float f; unsigned int i; } x; x.f = f;
    unsigned int r = (x.i + 0x7FFFu + ((x.i >> 16) & 1u)) >> 16;  // RNE
    return (unsigned short)r;
}

// Per-wave dtype sniff: low halves of fp32 words are random mantissa bits
// (~19% plausible bf16 exponents); true bf16 data is ~100% plausible.
// Uniform across the wave via ballot; requires all 64 lanes active.
__device__ static inline bool wave_detect_bf16(const unsigned int* __restrict__ p) {
    const int lane = threadIdx.x & 63;
    int cnt = 0;
#pragma unroll
    for (int r = 0; r < 4; ++r) {
        unsigned int w = p[r * 64 + lane];
        unsigned short lo = (unsigned short)(w & 0xFFFFu);
        int e = (lo >> 7) & 0xFF;
        bool plaus = (lo == 0) || (e >= 96 && e <= 144);
        cnt += (int)__popcll(__ballot(plaus));
    }
    return cnt >= 205;   // >=80% of 256 sampled halves
}

// ---------------- weight repack -> [9][256][128] bf16 ----------------------
__global__ void wt_repack(const void* __restrict__ wsrc,
                          unsigned short* __restrict__ wt) {
    const bool isbf = wave_detect_bf16((const unsigned int*)wsrc);
    int idx = blockIdx.x * 256 + threadIdx.x;       // 294912 total, grid=1152
    int ci  = idx & 127;
    int co  = (idx >> 7) & 255;
    int off = idx >> 15;                            // 0..8 = dh*3+dw
    size_t s = (size_t)(co * 128 + ci) * 9 + off;
    float v = isbf ? bf2f(((const unsigned short*)wsrc)[s])
                   : ((const float*)wsrc)[s];
    wt[idx] = f2bf(v);
}

// ------- x NCHW -> padded NHWC bf16 [32][58][58][128], LDS transpose -------
__global__ __launch_bounds__(256) void x_repack(
    const void* __restrict__ xsrc, unsigned short* __restrict__ xp) {
    __shared__ unsigned short tile[56 * 130];   // pad 130: conflict-free
    const int bh  = blockIdx.x;                 // 32*58 blocks
    const int b   = bh / 58, hp = bh - b * 58;  // hp in [0,58)
    const int tid = threadIdx.x;
    unsigned short* row = xp + (size_t)(b * 58 + hp) * 58 * 128;
    if (hp == 0 || hp == 57) {                  // top/bottom pad rows
        uint4 z; z.x = z.y = z.z = z.w = 0u;
        uint4* r = (uint4*)row;
        for (int t = tid; t < 928; t += 256) r[t] = z;
        return;
    }
    const bool isbf = wave_detect_bf16((const unsigned int*)xsrc);
    const int h = hp - 1;
    if (isbf) {
        const unsigned short* xs =
            (const unsigned short*)xsrc + (size_t)b * 128 * 3136 + h * 56;
#pragma unroll
        for (int it = 0; it < 7; ++it) {        // 1792 items = 128ci x 14 w4
            int idx = it * 256 + tid;
            int ci = idx / 14, w4 = idx - ci * 14;
            ushort4 v = *(const ushort4*)(xs + (size_t)ci * 3136 + w4 * 4);
            tile[(w4 * 4 + 0) * 130 + ci] = v.x;
            tile[(w4 * 4 + 1) * 130 + ci] = v.y;
            tile[(w4 * 4 + 2) * 130 + ci] = v.z;
            tile[(w4 * 4 + 3) * 130 + ci] = v.w;
        }
    } else {
        const float* xs = (const float*)xsrc + (size_t)b * 128 * 3136 + h * 56;
#pragma unroll
        for (int it = 0; it < 7; ++it) {
            int idx = it * 256 + tid;
            int ci = idx / 14, w4 = idx - ci * 14;
            float4 v = *(const float4*)(xs + (size_t)ci * 3136 + w4 * 4);
            tile[(w4 * 4 + 0) * 130 + ci] = f2bf(v.x);
            tile[(w4 * 4 + 1) * 130 + ci] = f2bf(v.y);
            tile[(w4 * 4 + 2) * 130 + ci] = f2bf(v.z);
            tile[(w4 * 4 + 3) * 130 + ci] = f2bf(v.w);
        }
    }
    __syncthreads();
#pragma unroll
    for (int it = 0; it < 4; ++it) {
        int k = it * 256 + tid;                 // 928 chunks of 16B
        if (k >= 928) break;
        int wq = k >> 4, cc = k & 15;
        uint4 v;
        if (wq == 0 || wq == 57) { v.x = v.y = v.z = v.w = 0u; }
        else {
            const unsigned short* p = &tile[(wq - 1) * 130 + cc * 8];
            union { unsigned short s[8]; uint4 u; } pk;
#pragma unroll
            for (int j = 0; j < 8; ++j) pk.s[j] = p[j];
            v = pk.u;
        }
        *(uint4*)(row + wq * 128 + cc * 8) = v;
    }
}

// -------- main: wave-specialized producer/consumer implicit GEMM -----------
__global__ __launch_bounds__(384) void conv_mfma(
    const unsigned short* __restrict__ xp,   // [32][58][58][128] bf16
    const unsigned short* __restrict__ wt,   // [9][256][128] bf16
    const void* __restrict__ bias,           // [256] fp32 or bf16
    void* __restrict__ out,                  // [32][256][56][56] fp32 or bf16
    const void* __restrict__ xorig)          // for dtype sniff only
{
    __shared__ __align__(16) char lds[49152];   // 3 buffers x (A 8KB | B 8KB)
    __shared__ unsigned ready[3];               // step tag: s+1 when loaded
    __shared__ unsigned freed[3];               // +4 per consumed step
    const int tid   = threadIdx.x;
    const int lane  = tid & 63;
    const int wv    = tid >> 6;        // 0..3 consumers, 4..5 producers
    const int ntile = blockIdx.x;      // 0..783 (spatial)
    const int mtile = blockIdx.y;      // 0..1   (cout)

    if (tid < 3) { ready[tid] = 0u; freed[tid] = 0u; }
    __syncthreads();                   // the ONLY barrier

    if (wv >= 4) {
        // ================= producer waves =================
        const int pid = wv - 4;                          // 0 or 1
        const int srp = lane >> 2;                       // row-in-16 group
        const int clg = (lane & 3) ^ ((lane >> 3) & 3);  // XOR chunk swizzle
        const unsigned short* aB = wt + (mtile * 128 + srp) * 128 + clg * 8;
        size_t bRow[8];
#pragma unroll
        for (int i = 0; i < 8; ++i) {
            const int n = ntile * 128 + i * 16 + srp;
            const int b = n / 3136, s2 = n - b * 3136;
            const int h = s2 / 56,  w = s2 - h * 56;
            bRow[i] = ((size_t)(b * 58 + h) * 58 + w) * 128 + clg * 8;
        }
        int bf_ = pid;                                   // s % 3 tracker
        for (int s = pid; s < 36; s += 2) {
            if (s >= 3) {
                const unsigned gate = 4u * (unsigned)(s / 3);
                while (__hip_atomic_load(&freed[bf_], __ATOMIC_ACQUIRE,
                                         __HIP_MEMORY_SCOPE_WORKGROUP) < gate)
                    __builtin_amdgcn_s_sleep(1);
            }
            char* buf = lds + bf_ * 16384;
            const int off = s >> 2, kb = (s & 3) << 5;   // off 0..8, kb 0..96
            const int dh = off / 3, dw = off - dh * 3;
            const int aoff = off * 32768 + kb;
            const int boff = (dh * 58 + dw) * 128 + kb;
#pragma unroll
            for (int i = 0; i < 8; ++i)
                gl2lds16(aB + i * 2048 + aoff, buf + i * 1024);
#pragma unroll
            for (int i = 0; i < 8; ++i)
                gl2lds16(xp + bRow[i] + boff, buf + 8192 + i * 1024);
            __builtin_amdgcn_s_waitcnt(0x3F70);          // vmcnt(0), this wave only
            if (lane == 0)
                __hip_atomic_store(&ready[bf_], (unsigned)(s + 1),
                                   __ATOMIC_RELEASE, __HIP_MEMORY_SCOPE_WORKGROUP);
            bf_ += 2; if (bf_ >= 3) bf_ -= 3;
        }
        return;
    }

    // ================= consumer waves =================
    const bool isbf = wave_detect_bf16((const unsigned int*)xorig);
    const int mbase = (wv >> 1) * 64 + (lane & 15);
    const int nbase = (wv & 1) * 64 + (lane & 15);
    const int ph    = (lane >> 4) ^ (((lane & 15) >> 1) & 3);
    floatx4 acc[4][4] = {};

#pragma unroll 3
    for (int s = 0; s < 36; ++s) {
        const int bf_ = s % 3;
        while (__hip_atomic_load(&ready[bf_], __ATOMIC_ACQUIRE,
                                 __HIP_MEMORY_SCOPE_WORKGROUP) < (unsigned)(s + 1))
            ;
        const char* la = lds + bf_ * 16384;
        const char* lb = la + 8192;
        short8 af[4], bfr[4];
#pragma unroll
        for (int t = 0; t < 4; ++t) {
            af[t]  = *(const short8*)(la + (mbase + t * 16) * 64 + ph * 16);
            bfr[t] = *(const short8*)(lb + (nbase + t * 16) * 64 + ph * 16);
        }
#pragma unroll
        for (int i = 0; i < 4; ++i)
#pragma unroll
            for (int j = 0; j < 4; ++j)
                acc[i][j] = __builtin_amdgcn_mfma_f32_16x16x32_bf16(
                    af[i], bfr[j], acc[i][j], 0, 0, 0);
        // release-add: fence drains this wave's ds_reads before buffer reuse
        if (lane == 0)
            __hip_atomic_fetch_add(&freed[bf_], 1u, __ATOMIC_RELEASE,
                                   __HIP_MEMORY_SCOPE_WORKGROUP);
    }

    // ---- epilogue: D[row=cout(quad*4+reg)][col=spatial(lane&15)]
    const int q = lane >> 4;
#pragma unroll
    for (int j = 0; j < 4; ++j) {
        const int n = ntile * 128 + (wv & 1) * 64 + j * 16 + (lane & 15);
        const int b = n / 3136;
        const int s = n - b * 3136;
#pragma unroll
        for (int i = 0; i < 4; ++i) {
            const int co = mtile * 128 + (wv >> 1) * 64 + i * 16 + q * 4;
            float bv[4];
            if (isbf) {
                const ushort4 bb = *(const ushort4*)((const unsigned short*)bias + co);
                bv[0] = bf2f(bb.x); bv[1] = bf2f(bb.y);
                bv[2] = bf2f(bb.z); bv[3] = bf2f(bb.w);
            } else {
                const float4 bb = *(const float4*)((const float*)bias + co);
                bv[0] = bb.x; bv[1] = bb.y; bv[2] = bb.z; bv[3] = bb.w;
            }
#pragma unroll
            for (int r = 0; r < 4; ++r) {
                const float v = acc[i][j][r] + bv[r];
                const size_t o = (size_t)b * 802816 + (size_t)(co + r) * 3136 + s;
                if (isbf) ((unsigned short*)out)[o] = f2bf(v);
                else      ((float*)out)[o] = v;
            }
        }
    }
}

// ---------------- fallback: naive direct conv fp32 (if ws too small) -------
__global__ void conv_naive(const float* __restrict__ x,
                           const float* __restrict__ w,
                           const float* __restrict__ bias,
                           float* __restrict__ out) {
    long long i = (long long)blockIdx.x * 256 + threadIdx.x;
    if (i >= 25690112LL) return;
    int wo = (int)(i % 56); long long t = i / 56;
    int ho = (int)(t % 56); t /= 56;
    int co = (int)(t % 256); int b = (int)(t / 256);
    float acc = bias[co];
    for (int ci = 0; ci < 128; ++ci)
        for (int dh = 0; dh < 3; ++dh) {
            int hi = ho + dh - 1; if ((unsigned)hi >= 56u) continue;
            for (int dw = 0; dw < 3; ++dw) {
                int wi = wo + dw - 1; if ((unsigned)wi >= 56u) continue;
                acc += x[((size_t)(b * 128 + ci) * 56 + hi) * 56 + wi] *
                       w[((co * 128 + ci) * 3 + dh) * 3 + dw];
            }
        }
    out[i] = acc;
}

extern "C" void kernel_launch(void* const* d_in, const int* in_sizes, int n_in,
                              void* d_out, int out_size, void* d_ws, size_t ws_size,
                              hipStream_t stream) {
    const void* x    = d_in[0];
    const void* w    = d_in[1];
    const void* bias = d_in[2];
    // d_in[3] = approximate (scalar, does not affect exact math) — unused.

    const size_t xp_bytes = (size_t)32 * 58 * 58 * 128 * 2;   // 27,557,888
    const size_t wt_off   = xp_bytes;
    const size_t wt_bytes = (size_t)9 * 256 * 128 * 2;        // 589,824
    const size_t need     = wt_off + wt_bytes;

    if (ws_size >= need) {
        unsigned short* xp = (unsigned short*)d_ws;
        unsigned short* wt = (unsigned short*)((char*)d_ws + wt_off);
        x_repack<<<32 * 58, 256, 0, stream>>>(x, xp);
        wt_repack<<<1152, 256, 0, stream>>>(w, wt);
        dim3 grid(784, 2, 1);
        conv_mfma<<<grid, 384, 0, stream>>>(xp, wt, bias, d_out, x);
    } else {
        conv_naive<<<(25690112 + 255) / 256, 256, 0, stream>>>(
            (const float*)x, (const float*)w, (const float*)bias, (float*)d_out);
    }
}